// Round 8
// baseline (546.012 us; speedup 1.0000x reference)
//
#include <hip/hip_runtime.h>
#include <math.h>

#define H1 56
#define W1 56
#define BB 16
#define NN 32
#define CC 512
#define MH 60
#define MW 60
#define OH 224
#define OW 224

typedef __bf16 bf16x8 __attribute__((ext_vector_type(8)));
typedef float floatx4 __attribute__((ext_vector_type(4)));

// ---------------- ws layout (float offsets), bf16 fast path ----------------
// mbh: 60*60*32*512 bf16 = 29,491,200 floats
#define MBH_OFF     0
#define F_YN_OFF    29491200
#define F_BEST0_OFF 29606400
#define F_BEST1_OFF 29656576
#define F_TMP1_OFF  29706752
#define F_TOTAL_FLOATS 29907456ull   // *4 = 119.6 MB

// ---------------- fallback layout (fp32 path) ----------------
#define S_XN_OFF   0
#define S_YN_OFF   50176
#define S_BEST_OFF 165376
#define S_TMP1_OFF 215552

// async global->LDS, 16B per lane, wave-uniform LDS base
#define GLOAD_LDS16(g, l) __builtin_amdgcn_global_load_lds( \
    (const __attribute__((address_space(1))) unsigned int*)(g), \
    (__attribute__((address_space(3))) unsigned int*)(l), 16, 0, 0)

// ---------------- convert + norm: one wave per 512-vector ----------------
__global__ void cvt_norm_kernel(const float* __restrict__ src, __bf16* __restrict__ dsth,
                                float* __restrict__ norm, int nvec) {
    int wid  = (int)((blockIdx.x * blockDim.x + threadIdx.x) >> 6);
    int lane = threadIdx.x & 63;
    if (wid >= nvec) return;
    const float* p = src + (size_t)wid * CC + lane * 8;
    floatx4 a = *(const floatx4*)p;
    floatx4 b = *(const floatx4*)(p + 4);
    if (dsth) {
        bf16x8 v;
        v[0] = (__bf16)a.x; v[1] = (__bf16)a.y; v[2] = (__bf16)a.z; v[3] = (__bf16)a.w;
        v[4] = (__bf16)b.x; v[5] = (__bf16)b.y; v[6] = (__bf16)b.z; v[7] = (__bf16)b.w;
        *(bf16x8*)(dsth + (size_t)wid * CC + lane * 8) = v;
    }
    float s = a.x*a.x + a.y*a.y + a.z*a.z + a.w*a.w
            + b.x*b.x + b.y*b.y + b.z*b.z + b.w*b.w;
    s += __shfl_xor(s, 32, 64);
    s += __shfl_xor(s, 16, 64);
    s += __shfl_xor(s, 8, 64);
    s += __shfl_xor(s, 4, 64);
    s += __shfl_xor(s, 2, 64);
    s += __shfl_xor(s, 1, 64);
    if (lane == 0) norm[wid] = s;
}

#define BSTRIDE 520   // bf16 elems; rows are 1024B contiguous + 16B pad (2-way LDS aliasing = free)
#define HROWS 16      // rows per half-position stage

// ---------------- main distance kernel: 2x4 emb tile, d1-split, grid 392x2 ----
// blockIdx.x = tile (XCD-swizzled), blockIdx.y = z in {0,1}: mb rows
// h0+3z .. h0+3z+2 (3 rows x 8 cols x 2 halves = 48 half-stages). Partial
// min written to best0/best1 by z; max_kernel merges. Grid 784 -> ~3 blocks/CU
// resident (VGPR 128 -> 4 max; LDS 36.3KB -> 4 max) = the TLP that grid 392
// couldn't deliver (1.53 blocks/CU, OccupancyPercent stuck at 15%).
__global__ __launch_bounds__(256, 2) void dist_kernel_bf16(
        const float* __restrict__ emb, const __bf16* __restrict__ mbh,
        const float* __restrict__ ynorm, float* __restrict__ best0,
        float* __restrict__ best1) {
    __shared__ __bf16 Bs[2][HROWS * BSTRIDE];
    __shared__ float Ys[3 * 8 * NN];

    int bx0  = blockIdx.x;
    int bx   = (bx0 & 7) * 49 + (bx0 >> 3);   // bijective XCD swizzle (392 = 8*49)
    int z    = blockIdx.y;                     // d1-range half: rows h0+3z..h0+3z+2
    float* bestz = z ? best1 : best0;
    int h0   = (bx / 14) * 2;
    int w0   = (bx % 14) * 4;
    int tid  = threadIdx.x;
    int wave = tid >> 6;
    int lane = tid & 63;
    int nrow = lane & 15;
    int seg  = lane >> 4;
    int w    = w0 + wave;

    // A fragments: load fp32 emb directly, convert in-register, norms in-register.
    bf16x8 afragA[16], afragB[16];
    float snA = 0.f, snB = 0.f;
    const float* apA = emb + ((size_t)(h0 * W1 + w) * BB + nrow) * CC + seg * 8;
    const float* apB = apA + (size_t)W1 * BB * CC;
#pragma unroll
    for (int kk = 0; kk < 16; kk++) {
        floatx4 a0 = *(const floatx4*)(apA + kk * 32);
        floatx4 a1 = *(const floatx4*)(apA + kk * 32 + 4);
        floatx4 b0 = *(const floatx4*)(apB + kk * 32);
        floatx4 b1 = *(const floatx4*)(apB + kk * 32 + 4);
        bf16x8 va, vb;
        va[0] = (__bf16)a0.x; va[1] = (__bf16)a0.y; va[2] = (__bf16)a0.z; va[3] = (__bf16)a0.w;
        va[4] = (__bf16)a1.x; va[5] = (__bf16)a1.y; va[6] = (__bf16)a1.z; va[7] = (__bf16)a1.w;
        vb[0] = (__bf16)b0.x; vb[1] = (__bf16)b0.y; vb[2] = (__bf16)b0.z; vb[3] = (__bf16)b0.w;
        vb[4] = (__bf16)b1.x; vb[5] = (__bf16)b1.y; vb[6] = (__bf16)b1.z; vb[7] = (__bf16)b1.w;
        afragA[kk] = va; afragB[kk] = vb;
        snA += a0.x*a0.x + a0.y*a0.y + a0.z*a0.z + a0.w*a0.w
             + a1.x*a1.x + a1.y*a1.y + a1.z*a1.z + a1.w*a1.w;
        snB += b0.x*b0.x + b0.y*b0.y + b0.z*b0.z + b0.w*b0.w
             + b1.x*b1.x + b1.y*b1.y + b1.z*b1.z + b1.w*b1.w;
    }
    // full row norms: sum over the 4 lanes sharing nrow (lane ^16, ^32)
    snA += __shfl_xor(snA, 16, 64); snA += __shfl_xor(snA, 32, 64);
    snB += __shfl_xor(snB, 16, 64); snB += __shfl_xor(snB, 32, 64);
    // redistribute: this lane accumulates batches seg*4+r
    floatx4 xnA, xnB;
#pragma unroll
    for (int r = 0; r < 4; r++) {
        xnA[r] = __shfl(snA, seg * 4 + r, 64);
        xnB[r] = __shfl(snB, seg * 4 + r, 64);
    }

    // stage ynorm tile into LDS: 3 rows (h0+3z..) x (8 cols x 32 n contiguous)
    for (int idx = tid; idx < 3 * 8 * NN; idx += 256) {
        int row = idx >> 8;              // / (8*32)
        int c   = idx & 255;
        Ys[idx] = ynorm[((size_t)((h0 + 3 * z + row) * MW + w0)) * NN + c];
    }

    float bvA[4] = {1e30f, 1e30f, 1e30f, 1e30f};
    float bvB[4] = {1e30f, 1e30f, 1e30f, 1e30f};

    // half-stage t in [0,48): local pos p = t>>1 (rrL = p>>3, j = p&7), n-half = t&1.
    // wave DMAs 4 rows (wave*4+tt) of the 16-row half, 1024B each.
    auto stage = [&](int t, int buf) {
        int p   = t >> 1;
        int hh  = t & 1;
        int rrL = p >> 3;
        int j   = p & 7;
        const __bf16* bp = mbh + ((size_t)((h0 + 3 * z + rrL) * MW + (w0 + j)) * NN
                                  + hh * HROWS) * CC;
#pragma unroll
        for (int tt = 0; tt < 4; tt++) {
            int n = wave * 4 + tt;
            GLOAD_LDS16(bp + (size_t)n * CC + lane * 8, &Bs[buf][n * BSTRIDE]);
        }
    };

    // prologue: stage half-stage 0 into buf 0
    stage(0, 0);
    __syncthreads();   // implicit vmcnt(0) drain + barrier (also commits Ys)

    for (int t = 0; t < 48; t++) {
        int cur = t & 1;
        if (t + 1 < 48) stage(t + 1, cur ^ 1);   // prefetch next half-stage

        int p   = t >> 1;
        int hh  = t & 1;
        int rrL = p >> 3;
        int j   = p & 7;
        int rr  = 3 * z + rrL;
        int d2  = j - wave;
        if (d2 >= 0 && d2 < 5) {
            const __bf16* Bc = &Bs[cur][0];
            float yn = Ys[(rrL * 8 + j) * NN + hh * 16 + nrow];
            floatx4 cA = {0,0,0,0}, cB = {0,0,0,0};
#pragma unroll
            for (int kk = 0; kk < 16; kk++) {
                bf16x8 b = *(const bf16x8*)(Bc + nrow * BSTRIDE + kk * 32 + seg * 8);
                cA = __builtin_amdgcn_mfma_f32_16x16x32_bf16(afragA[kk], b, cA, 0, 0, 0);
                cB = __builtin_amdgcn_mfma_f32_16x16x32_bf16(afragB[kk], b, cB, 0, 0, 0);
            }
            bool va = (rr < 5);      // row h0 uses d1 = rr
            bool vb = (rr >= 1);     // row h0+1 uses d1 = rr-1
#pragma unroll
            for (int r = 0; r < 4; r++) {
                float dA = fmaxf(xnA[r] - 2.f * cA[r] + yn, 0.f);
                float dB = fmaxf(xnB[r] - 2.f * cB[r] + yn, 0.f);
                bvA[r] = fminf(bvA[r], va ? dA : 1e30f);
                bvB[r] = fminf(bvB[r], vb ? dB : 1e30f);
            }
        }
        __syncthreads();   // drains prefetch DMA + WAR protection
    }

    // reduce min over the 16 n-lanes; write both rows (partial mins for this z)
#pragma unroll
    for (int r = 0; r < 4; r++) {
        float v = bvA[r];
        v = fminf(v, __shfl_xor(v, 1, 64));
        v = fminf(v, __shfl_xor(v, 2, 64));
        v = fminf(v, __shfl_xor(v, 4, 64));
        v = fminf(v, __shfl_xor(v, 8, 64));
        bvA[r] = v;
        float u = bvB[r];
        u = fminf(u, __shfl_xor(u, 1, 64));
        u = fminf(u, __shfl_xor(u, 2, 64));
        u = fminf(u, __shfl_xor(u, 4, 64));
        u = fminf(u, __shfl_xor(u, 8, 64));
        bvB[r] = u;
    }
    if ((lane & 15) == 0) {
        int posA = h0 * W1 + w;
        int posB = (h0 + 1) * W1 + w;
#pragma unroll
        for (int r = 0; r < 4; r++) {
            int b = seg * 4 + r;
            bestz[(size_t)b * (H1 * W1) + posA] = sqrtf(bvA[r]);
            bestz[(size_t)b * (H1 * W1) + posB] = sqrtf(bvB[r]);
        }
    }
}

// ---------------- fallback: fp32-staging dist (proven R2, 1x4 tile) ----------------
__global__ __launch_bounds__(256) void dist_kernel_f32(
        const float* __restrict__ emb, const float* __restrict__ mb,
        const float* __restrict__ xnorm, const float* __restrict__ ynorm,
        float* __restrict__ best) {
    __shared__ __bf16 Bs[NN * BSTRIDE];
    int bx   = blockIdx.x;
    int h    = bx / 14;
    int w0   = (bx % 14) * 4;
    int tid  = threadIdx.x;
    int wave = tid >> 6;
    int lane = tid & 63;
    int nrow = lane & 15;
    int seg  = lane >> 4;
    int w    = w0 + wave;

    bf16x8 afrag[16];
    const float* ap = emb + ((size_t)(h * W1 + w) * BB + nrow) * CC + seg * 8;
#pragma unroll
    for (int kk = 0; kk < 16; kk++) {
        floatx4 f0 = *(const floatx4*)(ap + kk * 32);
        floatx4 f1 = *(const floatx4*)(ap + kk * 32 + 4);
        bf16x8 v;
        v[0] = (__bf16)f0.x; v[1] = (__bf16)f0.y; v[2] = (__bf16)f0.z; v[3] = (__bf16)f0.w;
        v[4] = (__bf16)f1.x; v[5] = (__bf16)f1.y; v[6] = (__bf16)f1.z; v[7] = (__bf16)f1.w;
        afrag[kk] = v;
    }
    floatx4 xn = *(const floatx4*)(xnorm + (size_t)(h * W1 + w) * BB + seg * 4);
    float bestv[4] = {1e30f, 1e30f, 1e30f, 1e30f};

    for (int d1 = 0; d1 < 5; d1++) {
        int mr = h + d1;
        for (int j = 0; j < 8; j++) {
            int mc = w0 + j;
            const float* bp = mb + (size_t)(mr * MW + mc) * NN * CC;
            __syncthreads();
#pragma unroll
            for (int t = 0; t < 8; t++) {
                int c0 = t * 256 + tid;
                int n  = c0 >> 6;
                int ks = (c0 & 63) << 3;
                floatx4 f0 = *(const floatx4*)(bp + n * CC + ks);
                floatx4 f1 = *(const floatx4*)(bp + n * CC + ks + 4);
                bf16x8 v;
                v[0] = (__bf16)f0.x; v[1] = (__bf16)f0.y; v[2] = (__bf16)f0.z; v[3] = (__bf16)f0.w;
                v[4] = (__bf16)f1.x; v[5] = (__bf16)f1.y; v[6] = (__bf16)f1.z; v[7] = (__bf16)f1.w;
                *(bf16x8*)(&Bs[n * BSTRIDE + ks]) = v;
            }
            __syncthreads();

            int d2 = j - wave;
            if (d2 >= 0 && d2 < 5) {
                float yn0 = ynorm[(size_t)(mr * MW + mc) * NN + nrow];
                float yn1 = ynorm[(size_t)(mr * MW + mc) * NN + nrow + 16];
                floatx4 acc0 = {0,0,0,0};
                floatx4 acc1 = {0,0,0,0};
#pragma unroll
                for (int kk = 0; kk < 16; kk++) {
                    bf16x8 b0 = *(const bf16x8*)(&Bs[nrow * BSTRIDE + kk * 32 + seg * 8]);
                    bf16x8 b1 = *(const bf16x8*)(&Bs[(nrow + 16) * BSTRIDE + kk * 32 + seg * 8]);
                    acc0 = __builtin_amdgcn_mfma_f32_16x16x32_bf16(afrag[kk], b0, acc0, 0, 0, 0);
                    acc1 = __builtin_amdgcn_mfma_f32_16x16x32_bf16(afrag[kk], b1, acc1, 0, 0, 0);
                }
#pragma unroll
                for (int r = 0; r < 4; r++) {
                    float d0  = fmaxf(xn[r] - 2.f * acc0[r] + yn0, 0.f);
                    float d1v = fmaxf(xn[r] - 2.f * acc1[r] + yn1, 0.f);
                    bestv[r] = fminf(bestv[r], fminf(d0, d1v));
                }
            }
        }
    }
#pragma unroll
    for (int r = 0; r < 4; r++) {
        float v = bestv[r];
        v = fminf(v, __shfl_xor(v, 1, 64));
        v = fminf(v, __shfl_xor(v, 2, 64));
        v = fminf(v, __shfl_xor(v, 4, 64));
        v = fminf(v, __shfl_xor(v, 8, 64));
        bestv[r] = v;
    }
    if ((lane & 15) == 0) {
        int pos = h * W1 + w;
#pragma unroll
        for (int r = 0; r < 4; r++) {
            int b = seg * 4 + r;
            best[(size_t)b * (H1 * W1) + pos] = sqrtf(bestv[r]);
        }
    }
}

// ---------------- merge partial mins + per-batch max ----------------
// best0 <- min(best0, best1); out[b] = max over pixels. best1 may equal best0.
__global__ void max_kernel(float* __restrict__ best0, const float* __restrict__ best1,
                           float* __restrict__ out) {
    __shared__ float red[256];
    int b = blockIdx.x;
    float m = 0.f;
    for (int i = threadIdx.x; i < H1 * W1; i += 256) {
        size_t idx = (size_t)b * (H1 * W1) + i;
        float v = fminf(best0[idx], best1[idx]);
        best0[idx] = v;
        m = fmaxf(m, v);
    }
    red[threadIdx.x] = m;
    __syncthreads();
    for (int s = 128; s > 0; s >>= 1) {
        if (threadIdx.x < s) red[threadIdx.x] = fmaxf(red[threadIdx.x], red[threadIdx.x + s]);
        __syncthreads();
    }
    if (threadIdx.x == 0) out[b] = red[0];
}

// ---------------- fused blur: operate on low-res, fold bilinear into taps ----
struct GaussK { float k[33]; };

__device__ __forceinline__ int refl(int i, int n) {
    i = (i < 0) ? -i : i;
    i = (i > n - 1) ? 2 * (n - 1) - i : i;
    return i;
}

__global__ void vblur_kernel(const float* __restrict__ best, float* __restrict__ tmp1, GaussK g) {
    int idx = blockIdx.x * 256 + threadIdx.x;
    int lx = idx % W1;
    int y  = (idx / W1) % OH;
    int b  = idx / (W1 * OH);
    const float* p = best + (size_t)b * (H1 * W1);
    float acc = 0.f;
#pragma unroll
    for (int u = 0; u < 33; u++) {
        int z  = refl(y - 16 + u, OH);
        int rz = z & 3;
        float t = 0.125f + 0.25f * (float)((rz + 2) & 3);
        int lo = (z >> 2) + ((rz < 2) ? -1 : 0);
        int hi = min(lo + 1, H1 - 1);
        lo = max(lo, 0);
        acc += g.k[u] * ((1.f - t) * p[lo * W1 + lx] + t * p[hi * W1 + lx]);
    }
    tmp1[idx] = acc;
}

__global__ void hblur_kernel(const float* __restrict__ tmp1, float* __restrict__ dst, GaussK g) {
    int idx = blockIdx.x * 256 + threadIdx.x;
    int x = idx % OW;
    int y = (idx / OW) % OH;
    int b = idx / (OW * OH);
    const float* p = tmp1 + ((size_t)b * OH + y) * W1;
    float acc = 0.f;
#pragma unroll
    for (int u = 0; u < 33; u++) {
        int z  = refl(x - 16 + u, OW);
        int rz = z & 3;
        float t = 0.125f + 0.25f * (float)((rz + 2) & 3);
        int lo = (z >> 2) + ((rz < 2) ? -1 : 0);
        int hi = min(lo + 1, W1 - 1);
        lo = max(lo, 0);
        acc += g.k[u] * ((1.f - t) * p[lo] + t * p[hi]);
    }
    dst[idx] = acc;
}

extern "C" void kernel_launch(void* const* d_in, const int* in_sizes, int n_in,
                              void* d_out, int out_size, void* d_ws, size_t ws_size,
                              hipStream_t stream) {
    const float* emb = (const float*)d_in[0];
    const float* mbp = (const float*)d_in[1];
    float* ws  = (float*)d_ws;
    float* out = (float*)d_out;

    bool big = ws_size >= F_TOTAL_FLOATS * 4ull;

    float* best0;
    float* best1;
    float* tmp1;

    if (big) {
        __bf16* mbh  = (__bf16*)(ws + MBH_OFF);
        float* ynorm = ws + F_YN_OFF;
        best0 = ws + F_BEST0_OFF;
        best1 = ws + F_BEST1_OFF;
        tmp1  = ws + F_TMP1_OFF;
        cvt_norm_kernel<<<(MH * MW * NN) / 4, 256, 0, stream>>>(mbp, mbh, ynorm, MH * MW * NN);
        dist_kernel_bf16<<<dim3(28 * 14, 2), 256, 0, stream>>>(emb, mbh, ynorm, best0, best1);
    } else {
        float* xnorm = ws + S_XN_OFF;
        float* ynorm = ws + S_YN_OFF;
        best0 = ws + S_BEST_OFF;
        best1 = best0;
        tmp1  = ws + S_TMP1_OFF;
        cvt_norm_kernel<<<(H1 * W1 * BB) / 4, 256, 0, stream>>>(emb, nullptr, xnorm, H1 * W1 * BB);
        cvt_norm_kernel<<<(MH * MW * NN) / 4, 256, 0, stream>>>(mbp, nullptr, ynorm, MH * MW * NN);
        dist_kernel_f32<<<H1 * 14, 256, 0, stream>>>(emb, mbp, xnorm, ynorm, best0);
    }

    max_kernel<<<BB, 256, 0, stream>>>(best0, best1, out);

    GaussK g;
    {
        double wsum = 0.0, wd[33];
        for (int u = 0; u < 33; u++) {
            double xk = (u - 16) / 4.0;
            wd[u] = exp(-0.5 * xk * xk);
            wsum += wd[u];
        }
        for (int u = 0; u < 33; u++) g.k[u] = (float)(wd[u] / wsum);
    }
    vblur_kernel<<<(BB * OH * W1) / 256, 256, 0, stream>>>(best0, tmp1, g);
    hblur_kernel<<<(BB * OH * OW) / 256, 256, 0, stream>>>(tmp1, out + 16, g);
}

// Round 9
// 492.190 us; speedup vs baseline: 1.1094x; 1.1094x over previous
//
#include <hip/hip_runtime.h>
#include <math.h>

#define H1 56
#define W1 56
#define BB 16
#define NN 32
#define CC 512
#define MH 60
#define MW 60
#define OH 224
#define OW 224

typedef __bf16 bf16x8 __attribute__((ext_vector_type(8)));
typedef float floatx4 __attribute__((ext_vector_type(4)));

// ---------------- ws layout (float offsets), bf16 fast path ----------------
// mbh: 60*60*32*512 bf16 = 29,491,200 floats
#define MBH_OFF    0
#define F_YN_OFF   29491200
#define F_BEST_OFF 29606400
#define F_TMP1_OFF 29656576
#define F_TOTAL_FLOATS 29857280ull   // *4 = 119.4 MB

// ---------------- fallback layout (fp32 path) ----------------
#define S_XN_OFF   0
#define S_YN_OFF   50176
#define S_BEST_OFF 165376
#define S_TMP1_OFF 215552

// async global->LDS, 16B per lane, wave-uniform LDS base
#define GLOAD_LDS16(g, l) __builtin_amdgcn_global_load_lds( \
    (const __attribute__((address_space(1))) unsigned int*)(g), \
    (__attribute__((address_space(3))) unsigned int*)(l), 16, 0, 0)

// ---------------- convert + norm: one wave per 512-vector ----------------
__global__ void cvt_norm_kernel(const float* __restrict__ src, __bf16* __restrict__ dsth,
                                float* __restrict__ norm, int nvec) {
    int wid  = (int)((blockIdx.x * blockDim.x + threadIdx.x) >> 6);
    int lane = threadIdx.x & 63;
    if (wid >= nvec) return;
    const float* p = src + (size_t)wid * CC + lane * 8;
    floatx4 a = *(const floatx4*)p;
    floatx4 b = *(const floatx4*)(p + 4);
    if (dsth) {
        bf16x8 v;
        v[0] = (__bf16)a.x; v[1] = (__bf16)a.y; v[2] = (__bf16)a.z; v[3] = (__bf16)a.w;
        v[4] = (__bf16)b.x; v[5] = (__bf16)b.y; v[6] = (__bf16)b.z; v[7] = (__bf16)b.w;
        *(bf16x8*)(dsth + (size_t)wid * CC + lane * 8) = v;
    }
    float s = a.x*a.x + a.y*a.y + a.z*a.z + a.w*a.w
            + b.x*b.x + b.y*b.y + b.z*b.z + b.w*b.w;
    s += __shfl_xor(s, 32, 64);
    s += __shfl_xor(s, 16, 64);
    s += __shfl_xor(s, 8, 64);
    s += __shfl_xor(s, 4, 64);
    s += __shfl_xor(s, 2, 64);
    s += __shfl_xor(s, 1, 64);
    if (lane == 0) norm[wid] = s;
}

#define BSTRIDE 520   // bf16 elems; rows are 1024B contiguous + 16B pad (2-way LDS aliasing = free)

// ---------------- main distance kernel: 2x4 emb tile, async dbuf staging ----
// grid 392; 256 thr = 4 waves; wave owns emb (h0, w0+wave) and (h0+1, w0+wave).
// mb rows h0..h0+5 x cols w0..w0+7 staged once each: 48 stages.
// Pipeline: issue stage s+1 via global_load_lds into buf^1, compute MFMA on buf,
// single __syncthreads per stage (its implicit vmcnt(0) drain completes the DMA).
// NOTE (R3-R8 post-mortems): every structural alternative measured WORSE —
// counted-vmcnt 3-buf (157us), ring-4 half-stages (157us), direct-to-reg
// (250us), d1-split grid 784 (163us). Fewer/larger stages + 2-block/CU
// interleave is the empirically optimal point for this problem.
__global__ __launch_bounds__(256, 2) void dist_kernel_bf16(
        const float* __restrict__ emb, const __bf16* __restrict__ mbh,
        const float* __restrict__ ynorm, float* __restrict__ best) {
    __shared__ __bf16 Bs[2][NN * BSTRIDE];

    int bx0  = blockIdx.x;
    int bx   = (bx0 & 7) * 49 + (bx0 >> 3);   // bijective XCD swizzle (392 = 8*49)
    int h0   = (bx / 14) * 2;
    int w0   = (bx % 14) * 4;
    int tid  = threadIdx.x;
    int wave = tid >> 6;
    int lane = tid & 63;
    int nrow = lane & 15;
    int seg  = lane >> 4;
    int w    = w0 + wave;

    // A fragments: load fp32 emb directly, convert in-register, norms in-register.
    bf16x8 afragA[16], afragB[16];
    float snA = 0.f, snB = 0.f;
    const float* apA = emb + ((size_t)(h0 * W1 + w) * BB + nrow) * CC + seg * 8;
    const float* apB = apA + (size_t)W1 * BB * CC;
#pragma unroll
    for (int kk = 0; kk < 16; kk++) {
        floatx4 a0 = *(const floatx4*)(apA + kk * 32);
        floatx4 a1 = *(const floatx4*)(apA + kk * 32 + 4);
        floatx4 b0 = *(const floatx4*)(apB + kk * 32);
        floatx4 b1 = *(const floatx4*)(apB + kk * 32 + 4);
        bf16x8 va, vb;
        va[0] = (__bf16)a0.x; va[1] = (__bf16)a0.y; va[2] = (__bf16)a0.z; va[3] = (__bf16)a0.w;
        va[4] = (__bf16)a1.x; va[5] = (__bf16)a1.y; va[6] = (__bf16)a1.z; va[7] = (__bf16)a1.w;
        vb[0] = (__bf16)b0.x; vb[1] = (__bf16)b0.y; vb[2] = (__bf16)b0.z; vb[3] = (__bf16)b0.w;
        vb[4] = (__bf16)b1.x; vb[5] = (__bf16)b1.y; vb[6] = (__bf16)b1.z; vb[7] = (__bf16)b1.w;
        afragA[kk] = va; afragB[kk] = vb;
        snA += a0.x*a0.x + a0.y*a0.y + a0.z*a0.z + a0.w*a0.w
             + a1.x*a1.x + a1.y*a1.y + a1.z*a1.z + a1.w*a1.w;
        snB += b0.x*b0.x + b0.y*b0.y + b0.z*b0.z + b0.w*b0.w
             + b1.x*b1.x + b1.y*b1.y + b1.z*b1.z + b1.w*b1.w;
    }
    // full row norms: sum over the 4 lanes sharing nrow (lane ^16, ^32)
    snA += __shfl_xor(snA, 16, 64); snA += __shfl_xor(snA, 32, 64);
    snB += __shfl_xor(snB, 16, 64); snB += __shfl_xor(snB, 32, 64);
    // redistribute: this lane accumulates batches seg*4+r
    floatx4 xnA, xnB;
#pragma unroll
    for (int r = 0; r < 4; r++) {
        xnA[r] = __shfl(snA, seg * 4 + r, 64);
        xnB[r] = __shfl(snB, seg * 4 + r, 64);
    }

    float bvA[4] = {1e30f, 1e30f, 1e30f, 1e30f};
    float bvB[4] = {1e30f, 1e30f, 1e30f, 1e30f};

    // prologue: DMA stage 0 into buf 0 (wave loads rows t*4+wave, 1024B each)
    {
        const __bf16* bp = mbh + (size_t)(h0 * MW + w0) * NN * CC;
#pragma unroll
        for (int t = 0; t < 8; t++) {
            int n = t * 4 + wave;
            GLOAD_LDS16(bp + (size_t)n * CC + lane * 8, &Bs[0][n * BSTRIDE]);
        }
    }
    __syncthreads();   // implicit vmcnt(0) drain + barrier

    int sidx = 0;
    for (int rr = 0; rr < 6; rr++) {
        int mr = h0 + rr;
        for (int j = 0; j < 8; j++, sidx++) {
            int cur = sidx & 1;
            // issue next stage's DMA before computing current
            if (sidx + 1 < 48) {
                int nrr = rr + ((j + 1) >> 3);
                int nj  = (j + 1) & 7;
                const __bf16* bp = mbh + (size_t)((h0 + nrr) * MW + (w0 + nj)) * NN * CC;
#pragma unroll
                for (int t = 0; t < 8; t++) {
                    int n = t * 4 + wave;
                    GLOAD_LDS16(bp + (size_t)n * CC + lane * 8, &Bs[cur ^ 1][n * BSTRIDE]);
                }
            }

            int mc = w0 + j;
            int d2 = j - wave;
            if (d2 >= 0 && d2 < 5) {
                const __bf16* Bc = &Bs[cur][0];
                bool a0 = (rr < 5);      // row h0 uses d1 = rr
                bool a1 = (rr >= 1);     // row h0+1 uses d1 = rr-1
                float yn0 = ynorm[(size_t)(mr * MW + mc) * NN + nrow];
                float yn1 = ynorm[(size_t)(mr * MW + mc) * NN + nrow + 16];
                if (a0 && a1) {
                    floatx4 c0 = {0,0,0,0}, c1 = {0,0,0,0}, c2 = {0,0,0,0}, c3 = {0,0,0,0};
#pragma unroll
                    for (int kk = 0; kk < 16; kk++) {
                        bf16x8 b0 = *(const bf16x8*)(Bc + nrow * BSTRIDE + kk * 32 + seg * 8);
                        bf16x8 b1 = *(const bf16x8*)(Bc + (nrow + 16) * BSTRIDE + kk * 32 + seg * 8);
                        c0 = __builtin_amdgcn_mfma_f32_16x16x32_bf16(afragA[kk], b0, c0, 0, 0, 0);
                        c1 = __builtin_amdgcn_mfma_f32_16x16x32_bf16(afragA[kk], b1, c1, 0, 0, 0);
                        c2 = __builtin_amdgcn_mfma_f32_16x16x32_bf16(afragB[kk], b0, c2, 0, 0, 0);
                        c3 = __builtin_amdgcn_mfma_f32_16x16x32_bf16(afragB[kk], b1, c3, 0, 0, 0);
                    }
#pragma unroll
                    for (int r = 0; r < 4; r++) {
                        bvA[r] = fminf(bvA[r], fminf(fmaxf(xnA[r] - 2.f * c0[r] + yn0, 0.f),
                                                     fmaxf(xnA[r] - 2.f * c1[r] + yn1, 0.f)));
                        bvB[r] = fminf(bvB[r], fminf(fmaxf(xnB[r] - 2.f * c2[r] + yn0, 0.f),
                                                     fmaxf(xnB[r] - 2.f * c3[r] + yn1, 0.f)));
                    }
                } else if (a0) {
                    floatx4 c0 = {0,0,0,0}, c1 = {0,0,0,0};
#pragma unroll
                    for (int kk = 0; kk < 16; kk++) {
                        bf16x8 b0 = *(const bf16x8*)(Bc + nrow * BSTRIDE + kk * 32 + seg * 8);
                        bf16x8 b1 = *(const bf16x8*)(Bc + (nrow + 16) * BSTRIDE + kk * 32 + seg * 8);
                        c0 = __builtin_amdgcn_mfma_f32_16x16x32_bf16(afragA[kk], b0, c0, 0, 0, 0);
                        c1 = __builtin_amdgcn_mfma_f32_16x16x32_bf16(afragA[kk], b1, c1, 0, 0, 0);
                    }
#pragma unroll
                    for (int r = 0; r < 4; r++)
                        bvA[r] = fminf(bvA[r], fminf(fmaxf(xnA[r] - 2.f * c0[r] + yn0, 0.f),
                                                     fmaxf(xnA[r] - 2.f * c1[r] + yn1, 0.f)));
                } else {
                    floatx4 c2 = {0,0,0,0}, c3 = {0,0,0,0};
#pragma unroll
                    for (int kk = 0; kk < 16; kk++) {
                        bf16x8 b0 = *(const bf16x8*)(Bc + nrow * BSTRIDE + kk * 32 + seg * 8);
                        bf16x8 b1 = *(const bf16x8*)(Bc + (nrow + 16) * BSTRIDE + kk * 32 + seg * 8);
                        c2 = __builtin_amdgcn_mfma_f32_16x16x32_bf16(afragB[kk], b0, c2, 0, 0, 0);
                        c3 = __builtin_amdgcn_mfma_f32_16x16x32_bf16(afragB[kk], b1, c3, 0, 0, 0);
                    }
#pragma unroll
                    for (int r = 0; r < 4; r++)
                        bvB[r] = fminf(bvB[r], fminf(fmaxf(xnB[r] - 2.f * c2[r] + yn0, 0.f),
                                                     fmaxf(xnB[r] - 2.f * c3[r] + yn1, 0.f)));
                }
            }
            __syncthreads();   // drains next-stage DMA (vmcnt 0) + barrier
        }
    }

    // reduce min over the 16 n-lanes; write both rows
#pragma unroll
    for (int r = 0; r < 4; r++) {
        float v = bvA[r];
        v = fminf(v, __shfl_xor(v, 1, 64));
        v = fminf(v, __shfl_xor(v, 2, 64));
        v = fminf(v, __shfl_xor(v, 4, 64));
        v = fminf(v, __shfl_xor(v, 8, 64));
        bvA[r] = v;
        float u = bvB[r];
        u = fminf(u, __shfl_xor(u, 1, 64));
        u = fminf(u, __shfl_xor(u, 2, 64));
        u = fminf(u, __shfl_xor(u, 4, 64));
        u = fminf(u, __shfl_xor(u, 8, 64));
        bvB[r] = u;
    }
    if ((lane & 15) == 0) {
        int posA = h0 * W1 + w;
        int posB = (h0 + 1) * W1 + w;
#pragma unroll
        for (int r = 0; r < 4; r++) {
            int b = seg * 4 + r;
            best[(size_t)b * (H1 * W1) + posA] = sqrtf(bvA[r]);
            best[(size_t)b * (H1 * W1) + posB] = sqrtf(bvB[r]);
        }
    }
}

// ---------------- fallback: fp32-staging dist (proven R2, 1x4 tile) ----------------
__global__ __launch_bounds__(256) void dist_kernel_f32(
        const float* __restrict__ emb, const float* __restrict__ mb,
        const float* __restrict__ xnorm, const float* __restrict__ ynorm,
        float* __restrict__ best) {
    __shared__ __bf16 Bs[NN * BSTRIDE];
    int bx   = blockIdx.x;
    int h    = bx / 14;
    int w0   = (bx % 14) * 4;
    int tid  = threadIdx.x;
    int wave = tid >> 6;
    int lane = tid & 63;
    int nrow = lane & 15;
    int seg  = lane >> 4;
    int w    = w0 + wave;

    bf16x8 afrag[16];
    const float* ap = emb + ((size_t)(h * W1 + w) * BB + nrow) * CC + seg * 8;
#pragma unroll
    for (int kk = 0; kk < 16; kk++) {
        floatx4 f0 = *(const floatx4*)(ap + kk * 32);
        floatx4 f1 = *(const floatx4*)(ap + kk * 32 + 4);
        bf16x8 v;
        v[0] = (__bf16)f0.x; v[1] = (__bf16)f0.y; v[2] = (__bf16)f0.z; v[3] = (__bf16)f0.w;
        v[4] = (__bf16)f1.x; v[5] = (__bf16)f1.y; v[6] = (__bf16)f1.z; v[7] = (__bf16)f1.w;
        afrag[kk] = v;
    }
    floatx4 xn = *(const floatx4*)(xnorm + (size_t)(h * W1 + w) * BB + seg * 4);
    float bestv[4] = {1e30f, 1e30f, 1e30f, 1e30f};

    for (int d1 = 0; d1 < 5; d1++) {
        int mr = h + d1;
        for (int j = 0; j < 8; j++) {
            int mc = w0 + j;
            const float* bp = mb + (size_t)(mr * MW + mc) * NN * CC;
            __syncthreads();
#pragma unroll
            for (int t = 0; t < 8; t++) {
                int c0 = t * 256 + tid;
                int n  = c0 >> 6;
                int ks = (c0 & 63) << 3;
                floatx4 f0 = *(const floatx4*)(bp + n * CC + ks);
                floatx4 f1 = *(const floatx4*)(bp + n * CC + ks + 4);
                bf16x8 v;
                v[0] = (__bf16)f0.x; v[1] = (__bf16)f0.y; v[2] = (__bf16)f0.z; v[3] = (__bf16)f0.w;
                v[4] = (__bf16)f1.x; v[5] = (__bf16)f1.y; v[6] = (__bf16)f1.z; v[7] = (__bf16)f1.w;
                *(bf16x8*)(&Bs[n * BSTRIDE + ks]) = v;
            }
            __syncthreads();

            int d2 = j - wave;
            if (d2 >= 0 && d2 < 5) {
                float yn0 = ynorm[(size_t)(mr * MW + mc) * NN + nrow];
                float yn1 = ynorm[(size_t)(mr * MW + mc) * NN + nrow + 16];
                floatx4 acc0 = {0,0,0,0};
                floatx4 acc1 = {0,0,0,0};
#pragma unroll
                for (int kk = 0; kk < 16; kk++) {
                    bf16x8 b0 = *(const bf16x8*)(&Bs[nrow * BSTRIDE + kk * 32 + seg * 8]);
                    bf16x8 b1 = *(const bf16x8*)(&Bs[(nrow + 16) * BSTRIDE + kk * 32 + seg * 8]);
                    acc0 = __builtin_amdgcn_mfma_f32_16x16x32_bf16(afrag[kk], b0, acc0, 0, 0, 0);
                    acc1 = __builtin_amdgcn_mfma_f32_16x16x32_bf16(afrag[kk], b1, acc1, 0, 0, 0);
                }
#pragma unroll
                for (int r = 0; r < 4; r++) {
                    float d0  = fmaxf(xn[r] - 2.f * acc0[r] + yn0, 0.f);
                    float d1v = fmaxf(xn[r] - 2.f * acc1[r] + yn1, 0.f);
                    bestv[r] = fminf(bestv[r], fminf(d0, d1v));
                }
            }
        }
    }
#pragma unroll
    for (int r = 0; r < 4; r++) {
        float v = bestv[r];
        v = fminf(v, __shfl_xor(v, 1, 64));
        v = fminf(v, __shfl_xor(v, 2, 64));
        v = fminf(v, __shfl_xor(v, 4, 64));
        v = fminf(v, __shfl_xor(v, 8, 64));
        bestv[r] = v;
    }
    if ((lane & 15) == 0) {
        int pos = h * W1 + w;
#pragma unroll
        for (int r = 0; r < 4; r++) {
            int b = seg * 4 + r;
            best[(size_t)b * (H1 * W1) + pos] = sqrtf(bestv[r]);
        }
    }
}

// ---------------- img = per-batch max ----------------
__global__ void max_kernel(const float* __restrict__ best, float* __restrict__ out) {
    __shared__ float red[256];
    int b = blockIdx.x;
    float m = 0.f;
    for (int i = threadIdx.x; i < H1 * W1; i += 256)
        m = fmaxf(m, best[(size_t)b * (H1 * W1) + i]);
    red[threadIdx.x] = m;
    __syncthreads();
    for (int s = 128; s > 0; s >>= 1) {
        if (threadIdx.x < s) red[threadIdx.x] = fmaxf(red[threadIdx.x], red[threadIdx.x + s]);
        __syncthreads();
    }
    if (threadIdx.x == 0) out[b] = red[0];
}

// ---------------- fused blur: operate on low-res, fold bilinear into taps ----
struct GaussK { float k[33]; };

__device__ __forceinline__ int refl(int i, int n) {
    i = (i < 0) ? -i : i;
    i = (i > n - 1) ? 2 * (n - 1) - i : i;
    return i;
}

__global__ void vblur_kernel(const float* __restrict__ best, float* __restrict__ tmp1, GaussK g) {
    int idx = blockIdx.x * 256 + threadIdx.x;
    int lx = idx % W1;
    int y  = (idx / W1) % OH;
    int b  = idx / (W1 * OH);
    const float* p = best + (size_t)b * (H1 * W1);
    float acc = 0.f;
#pragma unroll
    for (int u = 0; u < 33; u++) {
        int z  = refl(y - 16 + u, OH);
        int rz = z & 3;
        float t = 0.125f + 0.25f * (float)((rz + 2) & 3);
        int lo = (z >> 2) + ((rz < 2) ? -1 : 0);
        int hi = min(lo + 1, H1 - 1);
        lo = max(lo, 0);
        acc += g.k[u] * ((1.f - t) * p[lo * W1 + lx] + t * p[hi * W1 + lx]);
    }
    tmp1[idx] = acc;
}

__global__ void hblur_kernel(const float* __restrict__ tmp1, float* __restrict__ dst, GaussK g) {
    int idx = blockIdx.x * 256 + threadIdx.x;
    int x = idx % OW;
    int y = (idx / OW) % OH;
    int b = idx / (OW * OH);
    const float* p = tmp1 + ((size_t)b * OH + y) * W1;
    float acc = 0.f;
#pragma unroll
    for (int u = 0; u < 33; u++) {
        int z  = refl(x - 16 + u, OW);
        int rz = z & 3;
        float t = 0.125f + 0.25f * (float)((rz + 2) & 3);
        int lo = (z >> 2) + ((rz < 2) ? -1 : 0);
        int hi = min(lo + 1, W1 - 1);
        lo = max(lo, 0);
        acc += g.k[u] * ((1.f - t) * p[lo] + t * p[hi]);
    }
    dst[idx] = acc;
}

extern "C" void kernel_launch(void* const* d_in, const int* in_sizes, int n_in,
                              void* d_out, int out_size, void* d_ws, size_t ws_size,
                              hipStream_t stream) {
    const float* emb = (const float*)d_in[0];
    const float* mbp = (const float*)d_in[1];
    float* ws  = (float*)d_ws;
    float* out = (float*)d_out;

    bool big = ws_size >= F_TOTAL_FLOATS * 4ull;

    float* best;
    float* tmp1;

    if (big) {
        __bf16* mbh  = (__bf16*)(ws + MBH_OFF);
        float* ynorm = ws + F_YN_OFF;
        best = ws + F_BEST_OFF;
        tmp1 = ws + F_TMP1_OFF;
        cvt_norm_kernel<<<(MH * MW * NN) / 4, 256, 0, stream>>>(mbp, mbh, ynorm, MH * MW * NN);
        dist_kernel_bf16<<<28 * 14, 256, 0, stream>>>(emb, mbh, ynorm, best);
    } else {
        float* xnorm = ws + S_XN_OFF;
        float* ynorm = ws + S_YN_OFF;
        best = ws + S_BEST_OFF;
        tmp1 = ws + S_TMP1_OFF;
        cvt_norm_kernel<<<(H1 * W1 * BB) / 4, 256, 0, stream>>>(emb, nullptr, xnorm, H1 * W1 * BB);
        cvt_norm_kernel<<<(MH * MW * NN) / 4, 256, 0, stream>>>(mbp, nullptr, ynorm, MH * MW * NN);
        dist_kernel_f32<<<H1 * 14, 256, 0, stream>>>(emb, mbp, xnorm, ynorm, best);
    }

    max_kernel<<<BB, 256, 0, stream>>>(best, out);

    GaussK g;
    {
        double wsum = 0.0, wd[33];
        for (int u = 0; u < 33; u++) {
            double xk = (u - 16) / 4.0;
            wd[u] = exp(-0.5 * xk * xk);
            wsum += wd[u];
        }
        for (int u = 0; u < 33; u++) g.k[u] = (float)(wd[u] / wsum);
    }
    vblur_kernel<<<(BB * OH * W1) / 256, 256, 0, stream>>>(best, tmp1, g);
    hblur_kernel<<<(BB * OH * OW) / 256, 256, 0, stream>>>(tmp1, out + 16, g);
}